// Round 1
// baseline (3782.121 us; speedup 1.0000x reference)
//
#include <hip/hip_runtime.h>
#include <math.h>

#define DEV_INLINE __device__ __forceinline__

constexpr int NB = 2048;   // batch
constexpr int C  = 64;     // d_k == d_v channels
constexpr int L  = 128;    // seq len == d_model
constexpr int DT = 32;     // d_trans
constexpr int NH = 16;     // heads
constexpr int KW = 13;
constexpr int PADC = 6;
constexpr float LN_EPS = 1e-3f;
constexpr float RTEMPER = 0.08838834764831845f; // 1/sqrt(128)

DEV_INLINE void fma4(float4& a, float s, const float4 w) {
    a.x = fmaf(s, w.x, a.x);
    a.y = fmaf(s, w.y, a.y);
    a.z = fmaf(s, w.z, a.z);
    a.w = fmaf(s, w.w, a.w);
}

// ---------------- K0: transpose proj_w (128 x 512) -> projT (512 x 128) ----
__global__ __launch_bounds__(256) void k0_transpose(const float* __restrict__ pw,
                                                    float* __restrict__ pt) {
    int idx = blockIdx.x * 256 + threadIdx.x;      // 65536 elems
    int j = idx >> 7, m = idx & 127;
    pt[j * 128 + m] = pw[m * 512 + j];
}

// ---------------- K1: conv1d (C=64 -> DT=32, kw=13, pad=6), one block/batch
__global__ __launch_bounds__(256) void k1_conv(const float* __restrict__ x,   // (NB,C,L)
                                               const float* __restrict__ wg,  // (DT,C,KW)
                                               const float* __restrict__ bias,// (DT)
                                               float* __restrict__ out)       // (NB,DT,L)
{
    __shared__ float xs[C * 140];    // padded rows: data at [6..133], stride 140
    __shared__ float wls[DT * 209];  // weight chunk: 16 c's, row stride 16*13+1

    const int b = blockIdx.x;
    const int tid = threadIdx.x;
    const float* xb = x + b * (C * L);

    for (int i = tid; i < C * L; i += 256) {
        int c = i >> 7, l = i & 127;
        xs[c * 140 + PADC + l] = xb[i];
    }
    for (int i = tid; i < C * 2 * PADC; i += 256) {
        int c = i / (2 * PADC), p = i % (2 * PADC);
        xs[c * 140 + (p < PADC ? p : L + p)] = 0.f;   // [0..5] and [134..139]
    }

    const int t  = tid >> 3;        // 0..31 output channel
    const int lq = tid & 7;         // 0..7
    const int l0 = lq << 4;         // 16 l-positions per thread

    float acc[16];
    const float bv = bias[t];
    #pragma unroll
    for (int j = 0; j < 16; ++j) acc[j] = bv;

    for (int ch = 0; ch < 4; ++ch) {
        __syncthreads();
        for (int i = tid; i < DT * 208; i += 256) {
            int tt = i / 208, r = i % 208;
            wls[tt * 209 + r] = wg[tt * (C * KW) + ch * 208 + r];
        }
        __syncthreads();
        for (int cc = 0; cc < 16; ++cc) {
            const int c = ch * 16 + cc;
            float xw[28];
            const float4* xr = (const float4*)(&xs[c * 140 + l0]);  // 16B aligned
            #pragma unroll
            for (int k4 = 0; k4 < 7; ++k4) {
                float4 vv = xr[k4];
                xw[k4*4+0] = vv.x; xw[k4*4+1] = vv.y; xw[k4*4+2] = vv.z; xw[k4*4+3] = vv.w;
            }
            const float* wr = &wls[t * 209 + cc * 13];
            #pragma unroll
            for (int kw = 0; kw < 13; ++kw) {
                const float w = wr[kw];
                #pragma unroll
                for (int j = 0; j < 16; ++j) acc[j] = fmaf(w, xw[j + kw], acc[j]);
            }
        }
    }
    float4* orow = (float4*)(out + b * (DT * L) + t * L + l0);
    #pragma unroll
    for (int j4 = 0; j4 < 4; ++j4)
        orow[j4] = make_float4(acc[j4*4+0], acc[j4*4+1], acc[j4*4+2], acc[j4*4+3]);
}

// ---- helper: qh[t][4g..4g+3] = sum_l src[t][l] * w[l][4g..4g+3] ----------
DEV_INLINE void mat_lw(const float* __restrict__ src, const float* __restrict__ wgl,
                       float* __restrict__ dst, int t, int g) {
    const float4* arow = (const float4*)(src + t * 132);
    const float4* wrow = ((const float4*)wgl) + g;
    float4 a4 = make_float4(0.f, 0.f, 0.f, 0.f);
    #pragma unroll 8
    for (int lc = 0; lc < 32; ++lc) {
        float4 av = arow[lc];
        fma4(a4, av.x, wrow[(4*lc+0)*8]);
        fma4(a4, av.y, wrow[(4*lc+1)*8]);
        fma4(a4, av.z, wrow[(4*lc+2)*8]);
        fma4(a4, av.w, wrow[(4*lc+3)*8]);
    }
    ((float4*)(dst + t * 36))[g] = a4;
}

// ---------------- K2: per-batch heads + attention + out-proj --------------
__global__ __launch_bounds__(256) void k2_attn(
    const float* __restrict__ qb, const float* __restrict__ kb, const float* __restrict__ vb,
    const float* __restrict__ wq, const float* __restrict__ wk, const float* __restrict__ wv,
    const float* __restrict__ projT,   // (512,128)
    const float* __restrict__ proj_b,  // (128)
    float* __restrict__ out3)          // (NB,DT,L)
{
    __shared__ float sQ[DT * 132];
    __shared__ float sK[DT * 132];
    __shared__ float sV[DT * 132];
    __shared__ float sqh[DT * 36];
    __shared__ float skh[DT * 36];
    __shared__ float svh[DT * 36];

    const int b = blockIdx.x, tid = threadIdx.x;
    for (int i = tid; i < DT * L; i += 256) {
        int t = i >> 7, l = i & 127;
        sQ[t * 132 + l] = qb[b * (DT * L) + i];
        sK[t * 132 + l] = kb[b * (DT * L) + i];
        sV[t * 132 + l] = vb[b * (DT * L) + i];
    }

    const int t = tid >> 3;     // 0..31 : row of everything this thread owns
    const int g = tid & 7;      // 0..7  : column-group
    const int base = tid & ~7;  // first lane of my 8-lane row-group

    // persistent proj accumulator: out3[t][g*16 .. g*16+15]
    float4 o3a[4];
    {
        const float4* pb4 = (const float4*)(proj_b + g * 16);
        #pragma unroll
        for (int j = 0; j < 4; ++j) o3a[j] = pb4[j];
    }
    __syncthreads();

    for (int h = 0; h < NH; ++h) {
        // qh/kh/vh = (32x128)@(128x32) per head, weights streamed from L1/L2
        mat_lw(sQ, wq + h * (L * DT), sqh, t, g);
        mat_lw(sK, wk + h * (L * DT), skh, t, g);
        mat_lw(sV, wv + h * (L * DT), svh, t, g);
        __syncthreads();

        // scores row t, cols tk = g + 8i ; softmax over 8-lane group
        float p[4];
        {
            float s[4] = {0.f, 0.f, 0.f, 0.f};
            const float4* qrow = (const float4*)(sqh + t * 36);
            #pragma unroll
            for (int dd = 0; dd < 8; ++dd) {
                float4 qv = qrow[dd];
                #pragma unroll
                for (int i = 0; i < 4; ++i) {
                    float4 kv = ((const float4*)(skh + (g + 8*i) * 36))[dd];
                    s[i] += qv.x*kv.x + qv.y*kv.y + qv.z*kv.z + qv.w*kv.w;
                }
            }
            #pragma unroll
            for (int i = 0; i < 4; ++i) s[i] *= RTEMPER;
            float mx = fmaxf(fmaxf(s[0], s[1]), fmaxf(s[2], s[3]));
            #pragma unroll
            for (int off = 1; off < 8; off <<= 1) mx = fmaxf(mx, __shfl_xor(mx, off, 64));
            float e[4], sum = 0.f;
            #pragma unroll
            for (int i = 0; i < 4; ++i) { e[i] = __expf(s[i] - mx); sum += e[i]; }
            #pragma unroll
            for (int off = 1; off < 8; off <<= 1) sum += __shfl_xor(sum, off, 64);
            const float inv = 1.f / sum;
            #pragma unroll
            for (int i = 0; i < 4; ++i) p[i] = e[i] * inv;
        }

        // O[t][4g..4g+3] = sum_tk at[t][tk] * vh[tk][4g..4g+3]
        float Or[4] = {0.f, 0.f, 0.f, 0.f};
        {
            const float4* vbase = (const float4*)svh;
            float4 a4 = make_float4(0.f, 0.f, 0.f, 0.f);
            #pragma unroll
            for (int tk = 0; tk < 32; ++tk) {
                float pv = __shfl(p[tk >> 3], base | (tk & 7), 64);
                fma4(a4, pv, vbase[tk * 9 + g]);
            }
            Or[0] = a4.x; Or[1] = a4.y; Or[2] = a4.z; Or[3] = a4.w;
        }

        // proj accumulate: o3[t][m] += sum_d O[t][d] * projT[h*32+d][m]
        {
            const float4* pTb = (const float4*)projT;
            #pragma unroll
            for (int d = 0; d < 32; ++d) {
                float ov = __shfl(Or[d & 3], base | (d >> 2), 64);
                const float4* prow = pTb + (h * 32 + d) * 32 + g * 4;
                #pragma unroll
                for (int j = 0; j < 4; ++j) fma4(o3a[j], ov, prow[j]);
            }
        }
        __syncthreads();   // protect sqh/skh/svh before next head overwrites
    }

    float4* orow = (float4*)(out3 + b * (DT * L) + t * L + g * 16);
    #pragma unroll
    for (int j = 0; j < 4; ++j) orow[j] = o3a[j];
}

// ---------------- K3: final conv (DT->C) + residual + LayerNorm -----------
__global__ __launch_bounds__(256) void k3_fconv_ln(
    const float* __restrict__ o3g,   // (NB,DT,L)
    const float* __restrict__ fcw,   // (C,DT,KW)
    const float* __restrict__ fcb,   // (C)
    const float* __restrict__ resid, // q: (NB,C,L)
    const float* __restrict__ ln_a, const float* __restrict__ ln_b,
    float* __restrict__ out)         // (NB,C,L)
{
    __shared__ float xs[DT * 140];    // padded o3 rows
    __shared__ float wls[16 * 417];   // chunk of 16 out-channels, stride 32*13+1

    const int b = blockIdx.x, tid = threadIdx.x;
    for (int i = tid; i < DT * L; i += 256) {
        int t = i >> 7, l = i & 127;
        xs[t * 140 + PADC + l] = o3g[b * (DT * L) + i];
    }
    for (int i = tid; i < DT * 2 * PADC; i += 256) {
        int t = i / (2 * PADC), p = i % (2 * PADC);
        xs[t * 140 + (p < PADC ? p : L + p)] = 0.f;
    }

    const int cq = tid >> 4;      // 0..15
    const int lq = tid & 15;      // 0..15
    const int l0 = lq << 3;       // 8 l-positions per thread

    for (int ch = 0; ch < 4; ++ch) {
        __syncthreads();
        for (int i = tid; i < 16 * 416; i += 256) {
            int ci = i / 416, r = i % 416;
            wls[ci * 417 + r] = fcw[(ch * 16 + ci) * 416 + r];
        }
        __syncthreads();

        const int c = ch * 16 + cq;
        float acc[8];
        const float bv = fcb[c];
        #pragma unroll
        for (int j = 0; j < 8; ++j) acc[j] = bv;

        for (int t = 0; t < DT; ++t) {
            float xw[20];
            const float4* xr = (const float4*)(&xs[t * 140 + l0]);  // 16B aligned
            #pragma unroll
            for (int k4 = 0; k4 < 5; ++k4) {
                float4 vv = xr[k4];
                xw[k4*4+0] = vv.x; xw[k4*4+1] = vv.y; xw[k4*4+2] = vv.z; xw[k4*4+3] = vv.w;
            }
            const float* wr = &wls[cq * 417 + t * 13];
            #pragma unroll
            for (int kw = 0; kw < 13; ++kw) {
                const float w = wr[kw];
                #pragma unroll
                for (int j = 0; j < 8; ++j) acc[j] = fmaf(w, xw[j + kw], acc[j]);
            }
        }
        // residual
        const float4* rr = (const float4*)(resid + b * (C * L) + c * L + l0);
        float4 r0 = rr[0], r1 = rr[1];
        acc[0] += r0.x; acc[1] += r0.y; acc[2] += r0.z; acc[3] += r0.w;
        acc[4] += r1.x; acc[5] += r1.y; acc[6] += r1.z; acc[7] += r1.w;

        // LayerNorm across the 16-lane group (whole row of 128)
        float s = 0.f;
        #pragma unroll
        for (int j = 0; j < 8; ++j) s += acc[j];
        #pragma unroll
        for (int off = 1; off < 16; off <<= 1) s += __shfl_xor(s, off, 64);
        const float mu = s * (1.f / 128.f);
        float d[8], ss = 0.f;
        #pragma unroll
        for (int j = 0; j < 8; ++j) { d[j] = acc[j] - mu; ss += d[j] * d[j]; }
        #pragma unroll
        for (int off = 1; off < 16; off <<= 1) ss += __shfl_xor(ss, off, 64);
        const float sigma = sqrtf(ss * (1.f / 127.f));
        const float inv = 1.f / (sigma + LN_EPS);

        const float4* la = (const float4*)(ln_a + l0);
        const float4* lb = (const float4*)(ln_b + l0);
        float4 A0 = la[0], A1 = la[1], B0 = lb[0], B1 = lb[1];
        float4 o0, o1;
        o0.x = fmaf(d[0] * inv, A0.x, B0.x);
        o0.y = fmaf(d[1] * inv, A0.y, B0.y);
        o0.z = fmaf(d[2] * inv, A0.z, B0.z);
        o0.w = fmaf(d[3] * inv, A0.w, B0.w);
        o1.x = fmaf(d[4] * inv, A1.x, B1.x);
        o1.y = fmaf(d[5] * inv, A1.y, B1.y);
        o1.z = fmaf(d[6] * inv, A1.z, B1.z);
        o1.w = fmaf(d[7] * inv, A1.w, B1.w);
        float4* ow = (float4*)(out + b * (C * L) + c * L + l0);
        ow[0] = o0; ow[1] = o1;
    }
}

extern "C" void kernel_launch(void* const* d_in, const int* in_sizes, int n_in,
                              void* d_out, int out_size, void* d_ws, size_t ws_size,
                              hipStream_t stream) {
    const float* q    = (const float*)d_in[0];
    const float* k    = (const float*)d_in[1];
    const float* v    = (const float*)d_in[2];
    const float* cq_w = (const float*)d_in[3];  const float* cq_b = (const float*)d_in[4];
    const float* ck_w = (const float*)d_in[5];  const float* ck_b = (const float*)d_in[6];
    const float* cv_w = (const float*)d_in[7];  const float* cv_b = (const float*)d_in[8];
    const float* w_qs = (const float*)d_in[9];
    const float* w_ks = (const float*)d_in[10];
    const float* w_vs = (const float*)d_in[11];
    const float* proj_w = (const float*)d_in[12];
    const float* proj_b = (const float*)d_in[13];
    const float* fc_w = (const float*)d_in[14]; const float* fc_b = (const float*)d_in[15];
    const float* ln_a = (const float*)d_in[16]; const float* ln_b = (const float*)d_in[17];
    float* out = (float*)d_out;

    // workspace layout (floats): qb | kb | vb | o3 | projT
    float* ws = (float*)d_ws;
    const size_t SZ = (size_t)NB * DT * L;   // 8,388,608
    float* qb = ws;
    float* kb = qb + SZ;
    float* vb = kb + SZ;
    float* o3 = vb + SZ;
    float* pT = o3 + SZ;                      // 512*128 floats

    k0_transpose<<<256, 256, 0, stream>>>(proj_w, pT);
    k1_conv<<<NB, 256, 0, stream>>>(q, cq_w, cq_b, qb);
    k1_conv<<<NB, 256, 0, stream>>>(k, ck_w, ck_b, kb);
    k1_conv<<<NB, 256, 0, stream>>>(v, cv_w, cv_b, vb);
    k2_attn<<<NB, 256, 0, stream>>>(qb, kb, vb, w_qs, w_ks, w_vs, pT, proj_b, o3);
    k3_fconv_ln<<<NB, 256, 0, stream>>>(o3, fc_w, fc_b, q, ln_a, ln_b, out);
}

// Round 2
// 1359.365 us; speedup vs baseline: 2.7823x; 2.7823x over previous
//
#include <hip/hip_runtime.h>
#include <math.h>

#define DEV_INLINE __device__ __forceinline__

constexpr int NB = 2048;   // batch
constexpr int C  = 64;     // d_k == d_v channels
constexpr int L  = 128;    // seq len == d_model
constexpr int DT = 32;     // d_trans
constexpr int NH = 16;     // heads
constexpr int KW = 13;
constexpr int PADC = 6;
constexpr float LN_EPS = 1e-3f;
constexpr float RTEMPER = 0.08838834764831845f; // 1/sqrt(128)

// MFMA fragment types (per cdna_hip_programming.md §3, compile-verified on gfx950)
using frag_ab = __attribute__((ext_vector_type(8))) short;  // 8 bf16
using frag_cd = __attribute__((ext_vector_type(4))) float;  // 4 fp32

union alignas(16) F16x8 { short s[8]; short4 h[2]; frag_ab f; };

DEV_INLINE short f2bf(float x) {   // fp32 -> bf16 RNE
    unsigned u = __float_as_uint(x);
    unsigned r = (u + 0x7FFFu + ((u >> 16) & 1u)) >> 16;
    return (short)r;
}

// ============ K0: pre-pack weights into B-fragment-ordered bf16 ============
// B-layout for mfma_f32_16x16x32_bf16: lane holds B[k][n], n=lane&15,
// k = (lane>>4)*8 + j.  w_qs/w_ks/w_vs: (H, L=128, DT=32) row-major.
// Frag order: [((h*8 + kt*2 + nt)*64 + lane)*8 + j],  k=kt*32+..., n=nt*16+...
// projB: B[k=d][n=m] = proj_w[m][h*32+d]; frag [((h*8 + nt8)*64 + lane)*8 + j]
__global__ __launch_bounds__(256) void k0_prep(
    const float* __restrict__ wqs, const float* __restrict__ wks,
    const float* __restrict__ wvs, const float* __restrict__ pw,
    short* __restrict__ wqB, short* __restrict__ wkB, short* __restrict__ wvB,
    short* __restrict__ projB)
{
    int idx = blockIdx.x * 256 + threadIdx.x;   // 32768 total
    int arr = idx >> 13;          // 0..3
    int rem = idx & 8191;         // (h*8 + f)*64 + lane
    int h   = rem >> 9;
    int f   = (rem >> 6) & 7;
    int ln  = rem & 63;
    F16x8 u;
    if (arr < 3) {
        const float* w = (arr == 0) ? wqs : (arr == 1 ? wks : wvs);
        int kt = f >> 1, nt = f & 1;
        int n = nt * 16 + (ln & 15);
        int kb = kt * 32 + ((ln >> 4) << 3);
        #pragma unroll
        for (int j = 0; j < 8; ++j)
            u.s[j] = f2bf(w[h * 4096 + (kb + j) * 32 + n]);
        short* dst = (arr == 0) ? wqB : (arr == 1 ? wkB : wvB);
        *(F16x8*)(dst + rem * 8) = u;
    } else {
        int m = f * 16 + (ln & 15);          // output column 0..127
        int db = (ln >> 4) << 3;             // d octet
        #pragma unroll
        for (int j = 0; j < 8; ++j)
            u.s[j] = f2bf(pw[m * 512 + h * 32 + db + j]);
        *(F16x8*)(projB + rem * 8) = u;
    }
}

// ============ K1: conv1d (C=64 -> DT=32), writes A-frag-ordered bf16 =======
// A-layout: lane holds A[m][k], m=lane&15, k=(lane>>4)*8+j.
// out frag order per batch: [((mt*4 + kt)*64 + lane)*8 + j], m=mt*16+..,k=kt*32+..
__global__ __launch_bounds__(256) void k1_conv(const float* __restrict__ x,   // (NB,C,L)
                                               const float* __restrict__ wg,  // (DT,C,KW)
                                               const float* __restrict__ bias,// (DT)
                                               short* __restrict__ outF)      // (NB, 4096) bf16 frags
{
    __shared__ float xs[C * 140];    // padded rows: data at [6..133], stride 140
    __shared__ float wls[DT * 209];  // weight chunk: 16 c's, row stride 16*13+1

    const int b = blockIdx.x;
    const int tid = threadIdx.x;
    const float* xb = x + b * (C * L);

    for (int i = tid; i < C * L; i += 256) {
        int c = i >> 7, l = i & 127;
        xs[c * 140 + PADC + l] = xb[i];
    }
    for (int i = tid; i < C * 2 * PADC; i += 256) {
        int c = i / (2 * PADC), p = i % (2 * PADC);
        xs[c * 140 + (p < PADC ? p : L + p)] = 0.f;
    }

    const int t  = tid >> 3;        // 0..31 output channel (row m)
    const int lq = tid & 7;         // 0..7
    const int l0 = lq << 4;         // 16 l-positions per thread

    float acc[16];
    const float bv = bias[t];
    #pragma unroll
    for (int j = 0; j < 16; ++j) acc[j] = bv;

    for (int ch = 0; ch < 4; ++ch) {
        __syncthreads();
        for (int i = tid; i < DT * 208; i += 256) {
            int tt = i / 208, r = i % 208;
            wls[tt * 209 + r] = wg[tt * (C * KW) + ch * 208 + r];
        }
        __syncthreads();
        for (int cc = 0; cc < 16; ++cc) {
            const int c = ch * 16 + cc;
            float xw[28];
            const float4* xr = (const float4*)(&xs[c * 140 + l0]);
            #pragma unroll
            for (int k4 = 0; k4 < 7; ++k4) {
                float4 vv = xr[k4];
                xw[k4*4+0] = vv.x; xw[k4*4+1] = vv.y; xw[k4*4+2] = vv.z; xw[k4*4+3] = vv.w;
            }
            const float* wr = &wls[t * 209 + cc * 13];
            #pragma unroll
            for (int kw = 0; kw < 13; ++kw) {
                const float w = wr[kw];
                #pragma unroll
                for (int j = 0; j < 16; ++j) acc[j] = fmaf(w, xw[j + kw], acc[j]);
            }
        }
    }
    // store bf16 in A-frag order: this thread owns m=t, k in [16lq, 16lq+16)
    // -> tile kt = lq>>1, octets o0=(lq&1)*2 and o0+1, lanes o*16 + (t&15)
    const int mt = t >> 4, kt = lq >> 1, o0 = (lq & 1) * 2;
    F16x8 u0, u1;
    #pragma unroll
    for (int j = 0; j < 8; ++j) { u0.s[j] = f2bf(acc[j]); u1.s[j] = f2bf(acc[8 + j]); }
    short* dst = outF + (size_t)b * 4096;
    const int base = ((mt * 4 + kt) * 64 + o0 * 16 + (t & 15)) * 8;
    *(F16x8*)(dst + base)       = u0;
    *(F16x8*)(dst + base + 128) = u1;   // next octet = lane+16
}

// ============ K2: MFMA heads + attention + out-proj ========================
// LDS bf16 tile buffers: 32 rows x stride 36 shorts (72B: 8B-aligned reads,
// ~2-way banks = free).  ld_frag reads an A/B fragment from row-major rows.
DEV_INLINE frag_ab ld_frag(const short* buf, int rbase, int lane) {
    const short* p = buf + (rbase + (lane & 15)) * 36 + ((lane >> 4) << 3);
    F16x8 u;
    u.h[0] = *(const short4*)p;
    u.h[1] = *(const short4*)(p + 4);
    return u.f;
}
DEV_INLINE void st_cfrag(short* buf, frag_cd c, int mt, int nt, int lane) {
    const int col = nt * 16 + (lane & 15);
    const int r0  = mt * 16 + ((lane >> 4) << 2);
    #pragma unroll
    for (int i = 0; i < 4; ++i) buf[(r0 + i) * 36 + col] = f2bf(c[i]);
}
DEV_INLINE void st_cfragT(short* buf, frag_cd c, int mt, int nt, int lane) {
    const int col = nt * 16 + (lane & 15);
    const int r0  = mt * 16 + ((lane >> 4) << 2);
    #pragma unroll
    for (int i = 0; i < 4; ++i) buf[col * 36 + r0 + i] = f2bf(c[i]);
}

// one projection: (32x128 A-frags in LDS) @ (128x32 B-frags in global) -> LDS tile
DEV_INLINE void do_proj(const short* aF, const short* bF, short* dst,
                        bool transp, int lane) {
    frag_ab B[8];
    #pragma unroll
    for (int i = 0; i < 8; ++i)                 // i = kt*2 + nt
        B[i] = *(const frag_ab*)(bF + (i * 64 + lane) * 8);
    #pragma unroll
    for (int mt = 0; mt < 2; ++mt) {
        frag_ab A[4];
        #pragma unroll
        for (int kt = 0; kt < 4; ++kt)
            A[kt] = *(const frag_ab*)(aF + ((mt * 4 + kt) * 64 + lane) * 8);
        #pragma unroll
        for (int nt = 0; nt < 2; ++nt) {
            frag_cd acc = {0.f, 0.f, 0.f, 0.f};
            #pragma unroll
            for (int kt = 0; kt < 4; ++kt)
                acc = __builtin_amdgcn_mfma_f32_16x16x32_bf16(A[kt], B[kt*2+nt], acc, 0, 0, 0);
            if (transp) st_cfragT(dst, acc, mt, nt, lane);
            else        st_cfrag (dst, acc, mt, nt, lane);
        }
    }
}

__global__ __launch_bounds__(256) void k2_attn(
    const short* __restrict__ qbF, const short* __restrict__ kbF, const short* __restrict__ vbF,
    const short* __restrict__ wqB, const short* __restrict__ wkB, const short* __restrict__ wvB,
    const short* __restrict__ projB, const float* __restrict__ proj_b,
    float* __restrict__ o3)          // (NB, DT, L) fp32
{
    __shared__ __align__(16) char smem_raw[24576 + 27648];   // 51 KB
    short* qkvA    = (short*)smem_raw;              // 3*8*64*8 = 12288 shorts
    short* scratch = (short*)(smem_raw + 24576);    // 4 waves * 3 bufs * 1152
    float* red     = (float*)(smem_raw + 24576);    // aliases scratch (16 KB)

    const int b = blockIdx.x, tid = threadIdx.x;
    const int lane = tid & 63, wv = tid >> 6;

    // stage qb/kb/vb fragments (already frag-ordered bf16): pure 16B copies
    for (int g = tid; g < 1536; g += 256) {
        const short* src = (g < 512 ? qbF : (g < 1024 ? kbF : vbF))
                           + (size_t)b * 4096 + (size_t)(g & 511) * 8;
        *(F16x8*)(qkvA + g * 8) = *(const F16x8*)src;
    }
    __syncthreads();

    short* buf0 = scratch + wv * 3456;   // qh rows, later P rows
    short* buf1 = buf0 + 1152;           // kh rows, later out rows
    short* buf2 = buf1 + 1152;           // vh^T rows (row d holds vh[:,d])

    frag_cd oc[2][8];                    // persistent proj accumulator (32x128)
    #pragma unroll
    for (int mt = 0; mt < 2; ++mt)
        #pragma unroll
        for (int n8 = 0; n8 < 8; ++n8)
            oc[mt][n8] = frag_cd{0.f, 0.f, 0.f, 0.f};

    for (int hi = 0; hi < 4; ++hi) {
        const int h = hi * 4 + wv;       // this wave's head
        // --- projections: qh, kh (rows), vh (transposed) ---
        do_proj(qkvA,        wqB + h * 4096, buf0, false, lane);
        do_proj(qkvA + 4096, wkB + h * 4096, buf1, false, lane);
        do_proj(qkvA + 8192, wvB + h * 4096, buf2, true,  lane);

        // --- scores = qh @ kh^T (K=32): B[k=d][n=tk] = kh[tk][d] ---
        frag_ab bk0 = ld_frag(buf1, 0, lane), bk1 = ld_frag(buf1, 16, lane);
        frag_cd S[2][2];
        #pragma unroll
        for (int mt = 0; mt < 2; ++mt) {
            frag_ab aq = ld_frag(buf0, mt * 16, lane);
            frag_cd z = {0.f, 0.f, 0.f, 0.f};
            S[mt][0] = __builtin_amdgcn_mfma_f32_16x16x32_bf16(aq, bk0, z, 0, 0, 0);
            S[mt][1] = __builtin_amdgcn_mfma_f32_16x16x32_bf16(aq, bk1, z, 0, 0, 0);
        }

        // --- softmax over rows (cols split lane&15 x nt), write P over buf0 ---
        #pragma unroll
        for (int mt = 0; mt < 2; ++mt) {
            #pragma unroll
            for (int i = 0; i < 4; ++i) {
                float s0 = S[mt][0][i] * RTEMPER;
                float s1 = S[mt][1][i] * RTEMPER;
                float mx = fmaxf(s0, s1);
                #pragma unroll
                for (int off = 1; off < 16; off <<= 1)
                    mx = fmaxf(mx, __shfl_xor(mx, off, 64));
                float e0 = __expf(s0 - mx), e1 = __expf(s1 - mx);
                float sm = e0 + e1;
                #pragma unroll
                for (int off = 1; off < 16; off <<= 1)
                    sm += __shfl_xor(sm, off, 64);
                const float inv = 1.f / sm;
                const int row = mt * 16 + ((lane >> 4) << 2) + i;
                buf0[row * 36 + (lane & 15)]      = f2bf(e0 * inv);
                buf0[row * 36 + 16 + (lane & 15)] = f2bf(e1 * inv);
            }
        }

        // --- out = P @ vh (K=32): B[k=tk][n=d] = vh[tk][d] = vhT rows ---
        frag_ab bv0 = ld_frag(buf2, 0, lane), bv1 = ld_frag(buf2, 16, lane);
        #pragma unroll
        for (int mt = 0; mt < 2; ++mt) {
            frag_ab ap = ld_frag(buf0, mt * 16, lane);
            frag_cd z = {0.f, 0.f, 0.f, 0.f};
            frag_cd O0 = __builtin_amdgcn_mfma_f32_16x16x32_bf16(ap, bv0, z, 0, 0, 0);
            frag_cd O1 = __builtin_amdgcn_mfma_f32_16x16x32_bf16(ap, bv1, z, 0, 0, 0);
            st_cfrag(buf1, O0, mt, 0, lane);
            st_cfrag(buf1, O1, mt, 1, lane);
        }

        // --- o3 += out @ projT_h : B[k=d][n=m] prepped in projB ---
        frag_ab ao0 = ld_frag(buf1, 0, lane), ao1 = ld_frag(buf1, 16, lane);
        #pragma unroll
        for (int n8 = 0; n8 < 8; ++n8) {
            frag_ab pb = *(const frag_ab*)(projB + h * 4096 + (n8 * 64 + lane) * 8);
            oc[0][n8] = __builtin_amdgcn_mfma_f32_16x16x32_bf16(ao0, pb, oc[0][n8], 0, 0, 0);
            oc[1][n8] = __builtin_amdgcn_mfma_f32_16x16x32_bf16(ao1, pb, oc[1][n8], 0, 0, 0);
        }
    }

    // --- cross-wave reduction of the 4 partial o3 copies ---
    __syncthreads();                     // scratch -> red reuse
    for (int w = 0; w < 4; ++w) {
        if (wv == w) {
            #pragma unroll
            for (int mt = 0; mt < 2; ++mt)
                #pragma unroll
                for (int n8 = 0; n8 < 8; ++n8)
                    #pragma unroll
                    for (int i = 0; i < 4; ++i) {
                        const int r = mt * 16 + ((lane >> 4) << 2) + i;
                        const int cix = n8 * 16 + (lane & 15);
                        const int ix = r * 128 + cix;
                        const float val = oc[mt][n8][i];
                        red[ix] = (w == 0) ? val : red[ix] + val;
                    }
        }
        __syncthreads();
    }
    float* o3b = o3 + (size_t)b * 4096;
    for (int i4 = tid; i4 < 1024; i4 += 256) {
        float4 vv = ((const float4*)red)[i4];
        float4 pb = ((const float4*)proj_b)[i4 & 31];
        vv.x += pb.x; vv.y += pb.y; vv.z += pb.z; vv.w += pb.w;
        ((float4*)o3b)[i4] = vv;
    }
}

// ============ K3: final conv (DT->C) + residual + LayerNorm ================
__global__ __launch_bounds__(256) void k3_fconv_ln(
    const float* __restrict__ o3g,   // (NB,DT,L)
    const float* __restrict__ fcw,   // (C,DT,KW)
    const float* __restrict__ fcb,   // (C)
    const float* __restrict__ resid, // q: (NB,C,L)
    const float* __restrict__ ln_a, const float* __restrict__ ln_b,
    float* __restrict__ out)         // (NB,C,L)
{
    __shared__ float xs[DT * 140];
    __shared__ float wls[16 * 417];

    const int b = blockIdx.x, tid = threadIdx.x;
    for (int i = tid; i < DT * L; i += 256) {
        int t = i >> 7, l = i & 127;
        xs[t * 140 + PADC + l] = o3g[b * (DT * L) + i];
    }
    for (int i = tid; i < DT * 2 * PADC; i += 256) {
        int t = i / (2 * PADC), p = i % (2 * PADC);
        xs[t * 140 + (p < PADC ? p : L + p)] = 0.f;
    }

    const int cq = tid >> 4;      // 0..15
    const int lq = tid & 15;      // 0..15
    const int l0 = lq << 3;       // 8 l-positions per thread

    for (int ch = 0; ch < 4; ++ch) {
        __syncthreads();
        for (int i = tid; i < 16 * 416; i += 256) {
            int ci = i / 416, r = i % 416;
            wls[ci * 417 + r] = fcw[(ch * 16 + ci) * 416 + r];
        }
        __syncthreads();

        const int c = ch * 16 + cq;
        float acc[8];
        const float bv = fcb[c];
        #pragma unroll
        for (int j = 0; j < 8; ++j) acc[j] = bv;

        for (int t = 0; t < DT; ++t) {
            float xw[20];
            const float4* xr = (const float4*)(&xs[t * 140 + l0]);
            #pragma unroll
            for (int k4 = 0; k4 < 5; ++k4) {
                float4 vv = xr[k4];
                xw[k4*4+0] = vv.x; xw[k4*4+1] = vv.y; xw[k4*4+2] = vv.z; xw[k4*4+3] = vv.w;
            }
            const float* wr = &wls[cq * 417 + t * 13];
            #pragma unroll
            for (int kw = 0; kw < 13; ++kw) {
                const float w = wr[kw];
                #pragma unroll
                for (int j = 0; j < 8; ++j) acc[j] = fmaf(w, xw[j + kw], acc[j]);
            }
        }
        const float4* rr = (const float4*)(resid + b * (C * L) + c * L + l0);
        float4 r0 = rr[0], r1 = rr[1];
        acc[0] += r0.x; acc[1] += r0.y; acc[2] += r0.z; acc[3] += r0.w;
        acc[4] += r1.x; acc[5] += r1.y; acc[6] += r1.z; acc[7] += r1.w;

        float s = 0.f;
        #pragma unroll
        for (int j = 0; j < 8; ++j) s += acc[j];
        #pragma unroll
        for (int off = 1; off < 16; off <<= 1) s += __shfl_xor(s, off, 64);
        const float mu = s * (1.f / 128.f);
        float d[8], ss = 0.f;
        #pragma unroll
        for (int j = 0; j < 8; ++j) { d[j] = acc[j] - mu; ss += d[j] * d[j]; }
        #pragma unroll
        for (int off = 1; off < 16; off <<= 1) ss += __shfl_xor(ss, off, 64);
        const float sigma = sqrtf(ss * (1.f / 127.f));
        const float inv = 1.f / (sigma + LN_EPS);

        const float4* la = (const float4*)(ln_a + l0);
        const float4* lb = (const float4*)(ln_b + l0);
        float4 A0 = la[0], A1 = la[1], B0 = lb[0], B1 = lb[1];
        float4 o0, o1;
        o0.x = fmaf(d[0] * inv, A0.x, B0.x);
        o0.y = fmaf(d[1] * inv, A0.y, B0.y);
        o0.z = fmaf(d[2] * inv, A0.z, B0.z);
        o0.w = fmaf(d[3] * inv, A0.w, B0.w);
        o1.x = fmaf(d[4] * inv, A1.x, B1.x);
        o1.y = fmaf(d[5] * inv, A1.y, B1.y);
        o1.z = fmaf(d[6] * inv, A1.z, B1.z);
        o1.w = fmaf(d[7] * inv, A1.w, B1.w);
        float4* ow = (float4*)(out + b * (C * L) + c * L + l0);
        ow[0] = o0; ow[1] = o1;
    }
}

extern "C" void kernel_launch(void* const* d_in, const int* in_sizes, int n_in,
                              void* d_out, int out_size, void* d_ws, size_t ws_size,
                              hipStream_t stream) {
    const float* q    = (const float*)d_in[0];
    const float* k    = (const float*)d_in[1];
    const float* v    = (const float*)d_in[2];
    const float* cq_w = (const float*)d_in[3];  const float* cq_b = (const float*)d_in[4];
    const float* ck_w = (const float*)d_in[5];  const float* ck_b = (const float*)d_in[6];
    const float* cv_w = (const float*)d_in[7];  const float* cv_b = (const float*)d_in[8];
    const float* w_qs = (const float*)d_in[9];
    const float* w_ks = (const float*)d_in[10];
    const float* w_vs = (const float*)d_in[11];
    const float* proj_w = (const float*)d_in[12];
    const float* proj_b = (const float*)d_in[13];
    const float* fc_w = (const float*)d_in[14]; const float* fc_b = (const float*)d_in[15];
    const float* ln_a = (const float*)d_in[16]; const float* ln_b = (const float*)d_in[17];
    float* out = (float*)d_out;

    // workspace: qbF|kbF|vbF (bf16 frag-order, 16.8MB ea) | o3 fp32 (33.5MB)
    //            | wqB|wkB|wvB|projB (bf16 frags, 128KB ea)   total ~84.4MB
    short* ws16 = (short*)d_ws;
    const size_t SZF = (size_t)NB * 4096;
    short* qbF = ws16;
    short* kbF = qbF + SZF;
    short* vbF = kbF + SZF;
    float* o3  = (float*)(vbF + SZF);
    short* wqB = (short*)(o3 + (size_t)NB * 4096);
    short* wkB = wqB + 65536;
    short* wvB = wkB + 65536;
    short* projB = wvB + 65536;

    k0_prep<<<128, 256, 0, stream>>>(w_qs, w_ks, w_vs, proj_w, wqB, wkB, wvB, projB);
    k1_conv<<<NB, 256, 0, stream>>>(q, cq_w, cq_b, qbF);
    k1_conv<<<NB, 256, 0, stream>>>(k, ck_w, ck_b, kbF);
    k1_conv<<<NB, 256, 0, stream>>>(v, cv_w, cv_b, vbF);
    k2_attn<<<NB, 256, 0, stream>>>(qbF, kbF, vbF, wqB, wkB, wvB, projB, proj_b, o3);
    k3_fconv_ln<<<NB, 256, 0, stream>>>(o3, fc_w, fc_b, q, ln_a, ln_b, out);
}

// Round 3
// 441.917 us; speedup vs baseline: 8.5584x; 3.0761x over previous
//
#include <hip/hip_runtime.h>
#include <math.h>

#define DEV_INLINE __device__ __forceinline__

constexpr int NB = 2048;   // batch
constexpr int C  = 64;     // d_k == d_v channels
constexpr int L  = 128;    // seq len == d_model
constexpr int DT = 32;     // d_trans
constexpr int NH = 16;     // heads
constexpr int KW = 13;
constexpr int PADC = 6;
constexpr float LN_EPS = 1e-3f;
constexpr float RTEMPER = 0.08838834764831845f; // 1/sqrt(128)

using frag_ab = __attribute__((ext_vector_type(8))) short;  // 8 bf16
using frag_cd = __attribute__((ext_vector_type(4))) float;  // 4 fp32

union alignas(16) F16x8 { short s[8]; short4 h[2]; frag_ab f; };

DEV_INLINE short f2bf(float x) {   // fp32 -> bf16 RNE
    unsigned u = __float_as_uint(x);
    unsigned r = (u + 0x7FFFu + ((u >> 16) & 1u)) >> 16;
    return (short)r;
}

// ============ K0: pre-pack ALL weights into MFMA-fragment-ordered bf16 =====
// B-layout (16x16x32): lane holds B[k][n], n=lane&15, k=(lane>>4)*8+j.
// A-layout:            lane holds A[m][k], m=lane&15, k=(lane>>4)*8+j.
// wq/wk/wv B-frags: [((h*8 + kt*2 + nt)*64 + lane)*8 + j]
// projB:            [((h*8 + n8)*64 + lane)*8 + j]
// conv1 A-frags:    [(((kw*2+kt)*2 + mt)*64 + lane)*8 + j]  (co=mt*16+.., ci=kt*32+..)
// fc    A-frags:    [((kw*4 + mt)*64 + lane)*8 + j]         (co=mt*16+.., t=..)
__global__ __launch_bounds__(256) void k0_prep(
    const float* __restrict__ wqs, const float* __restrict__ wks,
    const float* __restrict__ wvs, const float* __restrict__ pw,
    const float* __restrict__ cqw, const float* __restrict__ ckw,
    const float* __restrict__ cvw, const float* __restrict__ fcw,
    short* __restrict__ wqB, short* __restrict__ wkB, short* __restrict__ wvB,
    short* __restrict__ projB,
    short* __restrict__ cqA, short* __restrict__ ckA, short* __restrict__ cvA,
    short* __restrict__ fcA)
{
    int idx = blockIdx.x * 256 + threadIdx.x;   // 46080 total
    if (idx >= 46080) return;
    F16x8 u;
    if (idx < 32768) {
        int arr = idx >> 13;          // 0..3
        int rem = idx & 8191;         // (h*8 + f)*64 + lane
        int h   = rem >> 9;
        int f   = (rem >> 6) & 7;
        int ln  = rem & 63;
        if (arr < 3) {
            const float* w = (arr == 0) ? wqs : (arr == 1 ? wks : wvs);
            int kt = f >> 1, nt = f & 1;
            int n = nt * 16 + (ln & 15);
            int kb = kt * 32 + ((ln >> 4) << 3);
            #pragma unroll
            for (int j = 0; j < 8; ++j)
                u.s[j] = f2bf(w[h * 4096 + (kb + j) * 32 + n]);
            short* dst = (arr == 0) ? wqB : (arr == 1 ? wkB : wvB);
            *(F16x8*)(dst + rem * 8) = u;
        } else {
            int m = f * 16 + (ln & 15);
            int db = (ln >> 4) << 3;
            #pragma unroll
            for (int j = 0; j < 8; ++j)
                u.s[j] = f2bf(pw[m * 512 + h * 32 + db + j]);
            *(F16x8*)(projB + rem * 8) = u;
        }
    } else {
        int idx2 = idx - 32768;           // 0..13311
        int arr2 = idx2 / 3328;           // 0..3 : cq, ck, cv, fc
        int rem2 = idx2 - arr2 * 3328;    // slot = f*64 + lane
        int f  = rem2 >> 6;               // 0..51
        int ln = rem2 & 63;
        int q8 = (ln >> 4) << 3;
        if (arr2 < 3) {
            const float* w = (arr2 == 0) ? cqw : (arr2 == 1 ? ckw : cvw);
            int mt = f & 1, kt = (f >> 1) & 1, kw = f >> 2;
            int m = mt * 16 + (ln & 15);
            int cib = kt * 32 + q8;
            #pragma unroll
            for (int j = 0; j < 8; ++j)
                u.s[j] = f2bf(w[m * (C * KW) + (cib + j) * KW + kw]);
            short* dst = (arr2 == 0) ? cqA : (arr2 == 1 ? ckA : cvA);
            *(F16x8*)(dst + rem2 * 8) = u;
        } else {
            int mt = f & 3, kw = f >> 2;
            int m = mt * 16 + (ln & 15);
            #pragma unroll
            for (int j = 0; j < 8; ++j)
                u.s[j] = f2bf(fcw[m * (DT * KW) + (q8 + j) * KW + kw]);
            *(F16x8*)(fcA + rem2 * 8) = u;
        }
    }
}

// ============ K1: MFMA conv1d (C=64 -> DT=32), out = A-frag bf16 ===========
__global__ __launch_bounds__(256) void k1_conv(const float* __restrict__ x,   // (NB,C,L)
                                               const short* __restrict__ wA,  // packed A frags
                                               const float* __restrict__ bias,// (DT)
                                               short* __restrict__ outF)      // (NB,4096)
{
    __shared__ __align__(16) short xT[140 * 72];   // 20160 B
    __shared__ __align__(16) short ot[32 * 136];   // 8704 B (repack tile)

    const int b = blockIdx.x, tid = threadIdx.x;
    const int lane = tid & 63, wv = tid >> 6;
    const int q = lane >> 4, nlo = lane & 15;
    const float* xb = x + (size_t)b * (C * L);

    // stage + transpose + bf16: pack 2 channels per 4B LDS write
    for (int i = tid; i < 4096; i += 256) {
        int cp = i >> 7, l = i & 127;
        float a  = xb[(2 * cp) * 128 + l];
        float c2 = xb[(2 * cp + 1) * 128 + l];
        unsigned pk = (unsigned)(unsigned short)f2bf(a)
                    | ((unsigned)(unsigned short)f2bf(c2) << 16);
        *(unsigned*)&xT[(l + 6) * 72 + 2 * cp] = pk;
    }
    for (int i = tid; i < 768; i += 256) {         // zero pad rows, cols 0..63
        int rr = i >> 6, c = i & 63;
        int r = rr < 6 ? rr : 128 + rr;
        xT[r * 72 + c] = 0;
    }

    frag_cd acc[2][2];
    #pragma unroll
    for (int mt = 0; mt < 2; ++mt) {
        #pragma unroll
        for (int i = 0; i < 4; ++i) {
            float bv = bias[mt * 16 + q * 4 + i];
            acc[mt][0][i] = bv; acc[mt][1][i] = bv;
        }
    }
    __syncthreads();

    const int nb0 = wv * 32 + nlo;     // ntl=0 output position
    for (int f = 0; f < 26; ++f) {     // f = kw*2 + kt
        const int kw = f >> 1;
        frag_ab a0 = *(const frag_ab*)(wA + ((f * 2 + 0) * 64 + lane) * 8);
        frag_ab a1 = *(const frag_ab*)(wA + ((f * 2 + 1) * 64 + lane) * 8);
        const short* bp = &xT[(nb0 + kw) * 72 + (f & 1) * 32 + q * 8];
        frag_ab b0 = *(const frag_ab*)bp;
        frag_ab b1 = *(const frag_ab*)(bp + 16 * 72);
        acc[0][0] = __builtin_amdgcn_mfma_f32_16x16x32_bf16(a0, b0, acc[0][0], 0, 0, 0);
        acc[0][1] = __builtin_amdgcn_mfma_f32_16x16x32_bf16(a0, b1, acc[0][1], 0, 0, 0);
        acc[1][0] = __builtin_amdgcn_mfma_f32_16x16x32_bf16(a1, b0, acc[1][0], 0, 0, 0);
        acc[1][1] = __builtin_amdgcn_mfma_f32_16x16x32_bf16(a1, b1, acc[1][1], 0, 0, 0);
    }

    // C tiles -> LDS (t-major rows), then repack to A-frag order for k2
    #pragma unroll
    for (int mt = 0; mt < 2; ++mt)
        #pragma unroll
        for (int ntl = 0; ntl < 2; ++ntl) {
            int col = wv * 32 + ntl * 16 + nlo;
            int r0  = mt * 16 + q * 4;
            #pragma unroll
            for (int i = 0; i < 4; ++i)
                ot[(r0 + i) * 136 + col] = f2bf(acc[mt][ntl][i]);
        }
    __syncthreads();
    short* dst = outF + (size_t)b * 4096;
    #pragma unroll
    for (int s = wv; s < 8; s += 4) {   // s = mt*4 + kt
        int mt = s >> 2, kt = s & 3;
        const short* p = &ot[(mt * 16 + nlo) * 136 + kt * 32 + q * 8];
        F16x8 u; u.h[0] = *(const short4*)p; u.h[1] = *(const short4*)(p + 4);
        *(F16x8*)(dst + (s * 64 + lane) * 8) = u;
    }
}

// ============ K2: MFMA heads + attention + out-proj (verified R2) ==========
DEV_INLINE frag_ab ld_frag(const short* buf, int rbase, int lane) {
    const short* p = buf + (rbase + (lane & 15)) * 36 + ((lane >> 4) << 3);
    F16x8 u;
    u.h[0] = *(const short4*)p;
    u.h[1] = *(const short4*)(p + 4);
    return u.f;
}
DEV_INLINE void st_cfrag(short* buf, frag_cd c, int mt, int nt, int lane) {
    const int col = nt * 16 + (lane & 15);
    const int r0  = mt * 16 + ((lane >> 4) << 2);
    #pragma unroll
    for (int i = 0; i < 4; ++i) buf[(r0 + i) * 36 + col] = f2bf(c[i]);
}
DEV_INLINE void st_cfragT(short* buf, frag_cd c, int mt, int nt, int lane) {
    const int col = nt * 16 + (lane & 15);
    const int r0  = mt * 16 + ((lane >> 4) << 2);
    #pragma unroll
    for (int i = 0; i < 4; ++i) buf[col * 36 + r0 + i] = f2bf(c[i]);
}

DEV_INLINE void do_proj(const short* aF, const short* bF, short* dst,
                        bool transp, int lane) {
    frag_ab B[8];
    #pragma unroll
    for (int i = 0; i < 8; ++i)
        B[i] = *(const frag_ab*)(bF + (i * 64 + lane) * 8);
    #pragma unroll
    for (int mt = 0; mt < 2; ++mt) {
        frag_ab A[4];
        #pragma unroll
        for (int kt = 0; kt < 4; ++kt)
            A[kt] = *(const frag_ab*)(aF + ((mt * 4 + kt) * 64 + lane) * 8);
        #pragma unroll
        for (int nt = 0; nt < 2; ++nt) {
            frag_cd acc = {0.f, 0.f, 0.f, 0.f};
            #pragma unroll
            for (int kt = 0; kt < 4; ++kt)
                acc = __builtin_amdgcn_mfma_f32_16x16x32_bf16(A[kt], B[kt*2+nt], acc, 0, 0, 0);
            if (transp) st_cfragT(dst, acc, mt, nt, lane);
            else        st_cfrag (dst, acc, mt, nt, lane);
        }
    }
}

__global__ __launch_bounds__(256) void k2_attn(
    const short* __restrict__ qbF, const short* __restrict__ kbF, const short* __restrict__ vbF,
    const short* __restrict__ wqB, const short* __restrict__ wkB, const short* __restrict__ wvB,
    const short* __restrict__ projB, const float* __restrict__ proj_b,
    short* __restrict__ o3T)         // (NB, L=128, DT=32) bf16, l-major
{
    __shared__ __align__(16) char smem_raw[24576 + 27648];
    short* qkvA    = (short*)smem_raw;
    short* scratch = (short*)(smem_raw + 24576);
    float* red     = (float*)(smem_raw + 24576);

    const int b = blockIdx.x, tid = threadIdx.x;
    const int lane = tid & 63, wv = tid >> 6;

    for (int g = tid; g < 1536; g += 256) {
        const short* src = (g < 512 ? qbF : (g < 1024 ? kbF : vbF))
                           + (size_t)b * 4096 + (size_t)(g & 511) * 8;
        *(F16x8*)(qkvA + g * 8) = *(const F16x8*)src;
    }
    __syncthreads();

    short* buf0 = scratch + wv * 3456;
    short* buf1 = buf0 + 1152;
    short* buf2 = buf1 + 1152;

    frag_cd oc[2][8];
    #pragma unroll
    for (int mt = 0; mt < 2; ++mt)
        #pragma unroll
        for (int n8 = 0; n8 < 8; ++n8)
            oc[mt][n8] = frag_cd{0.f, 0.f, 0.f, 0.f};

    for (int hi = 0; hi < 4; ++hi) {
        const int h = hi * 4 + wv;
        do_proj(qkvA,        wqB + h * 4096, buf0, false, lane);
        do_proj(qkvA + 4096, wkB + h * 4096, buf1, false, lane);
        do_proj(qkvA + 8192, wvB + h * 4096, buf2, true,  lane);

        frag_ab bk0 = ld_frag(buf1, 0, lane), bk1 = ld_frag(buf1, 16, lane);
        frag_cd S[2][2];
        #pragma unroll
        for (int mt = 0; mt < 2; ++mt) {
            frag_ab aq = ld_frag(buf0, mt * 16, lane);
            frag_cd z = {0.f, 0.f, 0.f, 0.f};
            S[mt][0] = __builtin_amdgcn_mfma_f32_16x16x32_bf16(aq, bk0, z, 0, 0, 0);
            S[mt][1] = __builtin_amdgcn_mfma_f32_16x16x32_bf16(aq, bk1, z, 0, 0, 0);
        }

        #pragma unroll
        for (int mt = 0; mt < 2; ++mt) {
            #pragma unroll
            for (int i = 0; i < 4; ++i) {
                float s0 = S[mt][0][i] * RTEMPER;
                float s1 = S[mt][1][i] * RTEMPER;
                float mx = fmaxf(s0, s1);
                #pragma unroll
                for (int off = 1; off < 16; off <<= 1)
                    mx = fmaxf(mx, __shfl_xor(mx, off, 64));
                float e0 = __expf(s0 - mx), e1 = __expf(s1 - mx);
                float sm = e0 + e1;
                #pragma unroll
                for (int off = 1; off < 16; off <<= 1)
                    sm += __shfl_xor(sm, off, 64);
                const float inv = 1.f / sm;
                const int row = mt * 16 + ((lane >> 4) << 2) + i;
                buf0[row * 36 + (lane & 15)]      = f2bf(e0 * inv);
                buf0[row * 36 + 16 + (lane & 15)] = f2bf(e1 * inv);
            }
        }

        frag_ab bv0 = ld_frag(buf2, 0, lane), bv1 = ld_frag(buf2, 16, lane);
        #pragma unroll
        for (int mt = 0; mt < 2; ++mt) {
            frag_ab ap = ld_frag(buf0, mt * 16, lane);
            frag_cd z = {0.f, 0.f, 0.f, 0.f};
            frag_cd O0 = __builtin_amdgcn_mfma_f32_16x16x32_bf16(ap, bv0, z, 0, 0, 0);
            frag_cd O1 = __builtin_amdgcn_mfma_f32_16x16x32_bf16(ap, bv1, z, 0, 0, 0);
            st_cfrag(buf1, O0, mt, 0, lane);
            st_cfrag(buf1, O1, mt, 1, lane);
        }

        frag_ab ao0 = ld_frag(buf1, 0, lane), ao1 = ld_frag(buf1, 16, lane);
        #pragma unroll
        for (int n8 = 0; n8 < 8; ++n8) {
            frag_ab pb = *(const frag_ab*)(projB + h * 4096 + (n8 * 64 + lane) * 8);
            oc[0][n8] = __builtin_amdgcn_mfma_f32_16x16x32_bf16(ao0, pb, oc[0][n8], 0, 0, 0);
            oc[1][n8] = __builtin_amdgcn_mfma_f32_16x16x32_bf16(ao1, pb, oc[1][n8], 0, 0, 0);
        }
    }

    __syncthreads();
    for (int w = 0; w < 4; ++w) {
        if (wv == w) {
            #pragma unroll
            for (int mt = 0; mt < 2; ++mt)
                #pragma unroll
                for (int n8 = 0; n8 < 8; ++n8)
                    #pragma unroll
                    for (int i = 0; i < 4; ++i) {
                        const int r = mt * 16 + ((lane >> 4) << 2) + i;
                        const int cix = n8 * 16 + (lane & 15);
                        const int ix = r * 128 + cix;
                        const float val = oc[mt][n8][i];
                        red[ix] = (w == 0) ? val : red[ix] + val;
                    }
        }
        __syncthreads();
    }
    // write transposed bf16: o3T[b][l][t] = red[t][l] + proj_b[l]
    short* dst = o3T + (size_t)b * 4096;
    for (int i = tid; i < 4096; i += 256) {
        int l = i >> 5, t = i & 31;
        dst[i] = f2bf(red[t * 128 + l] + proj_b[l]);
    }
}

// ============ K3: MFMA final conv (DT->C) + residual + LayerNorm ===========
__global__ __launch_bounds__(256) void k3_fconv_ln(
    const short* __restrict__ o3T,   // (NB,128,32) bf16 l-major
    const short* __restrict__ fA,    // packed fc A-frags
    const float* __restrict__ fcb,
    const float* __restrict__ resid, // q: (NB,C,L)
    const float* __restrict__ ln_a, const float* __restrict__ ln_b,
    float* __restrict__ out)         // (NB,C,L)
{
    __shared__ __align__(16) short xT[140 * 40];   // 11200 B
    __shared__ __align__(16) float zb[64 * 132];   // 33792 B

    const int b = blockIdx.x, tid = threadIdx.x;
    const int lane = tid & 63, wv = tid >> 6;
    const int q = lane >> 4, nlo = lane & 15;

    const short* src = o3T + (size_t)b * 4096;
    for (int c = tid; c < 512; c += 256) {
        int l = c >> 2, t0 = (c & 3) * 8;
        *(F16x8*)(&xT[(l + 6) * 40 + t0]) = *(const F16x8*)(src + l * 32 + t0);
    }
    for (int i = tid; i < 384; i += 256) {
        int rr = i >> 5, cc = i & 31;
        int r = rr < 6 ? rr : 128 + rr;
        xT[r * 40 + cc] = 0;
    }

    frag_cd acc[4][2];
    #pragma unroll
    for (int mt = 0; mt < 4; ++mt) {
        #pragma unroll
        for (int i = 0; i < 4; ++i) {
            float bv = fcb[mt * 16 + q * 4 + i];
            acc[mt][0][i] = bv; acc[mt][1][i] = bv;
        }
    }
    __syncthreads();

    const int nb0 = wv * 32 + nlo;
    for (int kw = 0; kw < 13; ++kw) {
        frag_ab a[4];
        #pragma unroll
        for (int mt = 0; mt < 4; ++mt)
            a[mt] = *(const frag_ab*)(fA + ((kw * 4 + mt) * 64 + lane) * 8);
        const short* bp = &xT[(nb0 + kw) * 40 + q * 8];
        frag_ab b0 = *(const frag_ab*)bp;
        frag_ab b1 = *(const frag_ab*)(bp + 16 * 40);
        #pragma unroll
        for (int mt = 0; mt < 4; ++mt) {
            acc[mt][0] = __builtin_amdgcn_mfma_f32_16x16x32_bf16(a[mt], b0, acc[mt][0], 0, 0, 0);
            acc[mt][1] = __builtin_amdgcn_mfma_f32_16x16x32_bf16(a[mt], b1, acc[mt][1], 0, 0, 0);
        }
    }

    #pragma unroll
    for (int mt = 0; mt < 4; ++mt)
        #pragma unroll
        for (int ntl = 0; ntl < 2; ++ntl) {
            int col = wv * 32 + ntl * 16 + nlo;
            int r0  = mt * 16 + q * 4;
            #pragma unroll
            for (int i = 0; i < 4; ++i)
                zb[(r0 + i) * 132 + col] = acc[mt][ntl][i];
        }
    __syncthreads();

    const int cq = tid >> 4, lq = tid & 15, l0 = lq * 8;
    const float4* la4 = (const float4*)(ln_a + l0);
    const float4* lb4 = (const float4*)(ln_b + l0);
    float4 A0 = la4[0], A1 = la4[1], B0 = lb4[0], B1 = lb4[1];
    for (int g = 0; g < 4; ++g) {
        const int co = g * 16 + cq;
        const float4* zr4 = (const float4*)(&zb[co * 132 + l0]);
        float4 z0 = zr4[0], z1 = zr4[1];
        const float4* rr4 = (const float4*)(resid + (size_t)b * (C * L) + co * 128 + l0);
        float4 r0 = rr4[0], r1 = rr4[1];
        float zz[8] = {z0.x + r0.x, z0.y + r0.y, z0.z + r0.z, z0.w + r0.w,
                       z1.x + r1.x, z1.y + r1.y, z1.z + r1.z, z1.w + r1.w};
        float s = 0.f;
        #pragma unroll
        for (int j = 0; j < 8; ++j) s += zz[j];
        #pragma unroll
        for (int off = 1; off < 16; off <<= 1) s += __shfl_xor(s, off, 64);
        const float mu = s * (1.f / 128.f);
        float d[8], ss = 0.f;
        #pragma unroll
        for (int j = 0; j < 8; ++j) { d[j] = zz[j] - mu; ss += d[j] * d[j]; }
        #pragma unroll
        for (int off = 1; off < 16; off <<= 1) ss += __shfl_xor(ss, off, 64);
        const float sigma = sqrtf(ss * (1.f / 127.f));
        const float inv = 1.f / (sigma + LN_EPS);
        float4 o0, o1;
        o0.x = fmaf(d[0] * inv, A0.x, B0.x);
        o0.y = fmaf(d[1] * inv, A0.y, B0.y);
        o0.z = fmaf(d[2] * inv, A0.z, B0.z);
        o0.w = fmaf(d[3] * inv, A0.w, B0.w);
        o1.x = fmaf(d[4] * inv, A1.x, B1.x);
        o1.y = fmaf(d[5] * inv, A1.y, B1.y);
        o1.z = fmaf(d[6] * inv, A1.z, B1.z);
        o1.w = fmaf(d[7] * inv, A1.w, B1.w);
        float4* ow = (float4*)(out + (size_t)b * (C * L) + co * 128 + l0);
        ow[0] = o0; ow[1] = o1;
    }
}

extern "C" void kernel_launch(void* const* d_in, const int* in_sizes, int n_in,
                              void* d_out, int out_size, void* d_ws, size_t ws_size,
                              hipStream_t stream) {
    const float* q    = (const float*)d_in[0];
    const float* k    = (const float*)d_in[1];
    const float* v    = (const float*)d_in[2];
    const float* cq_w = (const float*)d_in[3];  const float* cq_b = (const float*)d_in[4];
    const float* ck_w = (const float*)d_in[5];  const float* ck_b = (const float*)d_in[6];
    const float* cv_w = (const float*)d_in[7];  const float* cv_b = (const float*)d_in[8];
    const float* w_qs = (const float*)d_in[9];
    const float* w_ks = (const float*)d_in[10];
    const float* w_vs = (const float*)d_in[11];
    const float* proj_w = (const float*)d_in[12];
    const float* proj_b = (const float*)d_in[13];
    const float* fc_w = (const float*)d_in[14]; const float* fc_b = (const float*)d_in[15];
    const float* ln_a = (const float*)d_in[16]; const float* ln_b = (const float*)d_in[17];
    float* out = (float*)d_out;

    short* ws16 = (short*)d_ws;
    const size_t SZF = (size_t)NB * 4096;
    short* qbF = ws16;
    short* kbF = qbF + SZF;
    short* vbF = kbF + SZF;
    short* o3T = vbF + SZF;
    short* wqB = o3T + SZF;
    short* wkB = wqB + 65536;
    short* wvB = wkB + 65536;
    short* projB = wvB + 65536;
    short* cqA = projB + 65536;
    short* ckA = cqA + 26624;
    short* cvA = ckA + 26624;
    short* fcA = cvA + 26624;

    k0_prep<<<180, 256, 0, stream>>>(w_qs, w_ks, w_vs, proj_w,
                                     cq_w, ck_w, cv_w, fc_w,
                                     wqB, wkB, wvB, projB, cqA, ckA, cvA, fcA);
    k1_conv<<<NB, 256, 0, stream>>>(q, cqA, cq_b, qbF);
    k1_conv<<<NB, 256, 0, stream>>>(k, ckA, ck_b, kbF);
    k1_conv<<<NB, 256, 0, stream>>>(v, cvA, cv_b, vbF);
    k2_attn<<<NB, 256, 0, stream>>>(qbF, kbF, vbF, wqB, wkB, wvB, projB, proj_b, o3T);
    k3_fconv_ln<<<NB, 256, 0, stream>>>(o3T, fcA, fc_b, q, ln_a, ln_b, out);
}